// Round 2
// 760.951 us; speedup vs baseline: 1.0398x; 1.0398x over previous
//
#include <hip/hip_runtime.h>
#include <hip/hip_bf16.h>
#include <stdint.h>

typedef __hip_bfloat16 bf16;
typedef __attribute__((ext_vector_type(4))) float f32x4;
typedef __attribute__((ext_vector_type(8))) short bf16x8;

// Problem constants
#define BB   8
#define TT   2048
#define DD   1024
#define MM   (BB * TT)   // 16384 rows

enum { EPI_Q = 0, EPI_K, EPI_V, EPI_ND, EPI_MLP1, EPI_MLP2 };

static __device__ __forceinline__ void async_ld16(const bf16* g, bf16* l) {
  __builtin_amdgcn_global_load_lds(
      (const __attribute__((address_space(1))) void*)g,
      (__attribute__((address_space(3))) void*)l, 16, 0, 0);
}

// ---------------------------------------------------------------------------
// Universal GEMM: C[M,N] = A[M,K] @ B[N,K]^T, A/B bf16 row-major (K inner).
//
// 256x256 tile, BK=32, 512 threads (8 waves as 2Mx4N, each owning 128x64).
// Deep pipeline: 4 LDS buffers (4 x (A 16KB + B 16KB) = 128 KiB); during
// K-tile t we stage K-tile t+3 into buf[(t+3)&3] == buf[(t-1)&3].  All
// ds_reads of that buffer completed before the tile t-1 phase-B barrier
// (every wave executes lgkmcnt(0) before it), and the stage is issued
// after that barrier -> race-free without region phasing.  vmcnt(8) once
// per K-tile (phase B) keeps 2 K-tiles of global_load_lds in flight
// ACROSS barriers (T3+T4); raw s_barrier (no vmcnt(0) drain); lgkmcnt(0)
// before each barrier so no ds_read is in flight when a newer stage-write
// can land; setprio(1) around each 16-MFMA cluster (T5).  Wrap-staging
// (tw masked) keeps exactly 4 loads/tile issued so the counted-vmcnt
// arithmetic stays uniform through the tail.
//
// LDS layout: buffer rows are 32 bf16 = 64 B. A fragment block (16 rows x
// 64 B) is 1024 contiguous bytes -> wave64 ds_read_b128 covers each bank
// pair exactly twice = conflict-free (m136); no swizzle needed, so
// global_load_lds destinations stay linear (rule #21).
//
// Grid is 1-D with bijective XCD swizzle (all nwg % 8 == 0). EPI_ND decodes
// batch from the top bits -> each XCD owns one batch (ew panel L2 reuse).
// Requires: M,N % 256 == 0; K % 32 == 0; K/32 a power of two >= 4.
// ---------------------------------------------------------------------------
template<int EPI>
__global__ __launch_bounds__(512, 2)
void gemm_bt(const bf16* __restrict__ A, const bf16* __restrict__ B,
             int M, int N, int K,
             long long strideAz, long long strideBz,
             float* __restrict__ Cf,
             bf16* __restrict__ Cb, long long strideCz,
             const float* __restrict__ bias,
             const float* __restrict__ add,
             bf16* __restrict__ ekv)
{
  (void)M;
  // A region: [0, 32768) elements (4 buffers x 8192), B: [32768, 65536)
  __shared__ __align__(16) bf16 lds[65536];

  const int tid  = threadIdx.x;
  const int wave = tid >> 6;
  const int lane = tid & 63;

  // ---- XCD-aware swizzle on 1-D grid (nwg % 8 == 0 for every launch) ----
  const int nwg = (int)gridDim.x;
  const int bid = (int)blockIdx.x;
  const int swz = (bid & 7) * (nwg >> 3) + (bid >> 3);
  int bn, bm, bz;
  if constexpr (EPI == EPI_ND) {       // batch = XCD
    bn = swz & 7; bm = (swz >> 3) & 7; bz = swz >> 6;
  } else {
    const int nbn = N >> 8;            // power of two (4 / 16 / 64)
    const int lnb = 31 - __clz(nbn);
    bn = swz & (nbn - 1); bm = swz >> lnb; bz = 0;
  }
  A += (size_t)bz * strideAz;
  B += (size_t)bz * strideBz;

  const int wm = (wave >> 2) * 128;    // wave's M offset in tile
  const int wn = (wave & 3) * 64;      // wave's N offset in tile

  // ---- staging addressing: per K-tile each thread issues 2 A + 2 B loads.
  // lane l -> row (wave*32 + (l>>2)), 16B chunk (l&3); LDS dest is the
  // wave-uniform segment base + lane*16 (linear, HW rule).
  const int lr = lane >> 2;            // 0..15
  const int lc = (lane & 3) * 8;       // element col within 32
  const bf16* Ag0 = A + ((size_t)bm * 256 + wave * 32 + lr) * K + lc;
  const bf16* Bg0 = B + ((size_t)bn * 256 + wave * 32 + lr) * K + lc;
  const size_t K16 = (size_t)16 * K;   // 16 rows
  const int ldsAW = wave * 1024;       // wave's segment (elements)
  const int ldsBW = 32768 + wave * 1024;
  const int NT = K >> 5;               // number of K-tiles (pow2, >= 32)

  auto stageA = [&](int tt) {
    const int bo = (tt & 3) * 8192;
    const bf16* g = Ag0 + (size_t)(tt & (NT - 1)) * 32;
    async_ld16(g,       &lds[bo + ldsAW]);
    async_ld16(g + K16, &lds[bo + ldsAW + 512]);
  };
  auto stageB = [&](int tt) {
    const int bo = (tt & 3) * 8192;
    const bf16* g = Bg0 + (size_t)(tt & (NT - 1)) * 32;
    async_ld16(g,       &lds[bo + ldsBW]);
    async_ld16(g + K16, &lds[bo + ldsBW + 512]);
  };

  f32x4 acc[8][4];
#pragma unroll
  for (int i = 0; i < 8; ++i)
#pragma unroll
    for (int j = 0; j < 4; ++j) acc[i][j] = {0.f, 0.f, 0.f, 0.f};

  // ---- prologue: stage K-tiles 0,1,2; wait tile 0 (8 newer may fly) ----
  stageA(0); stageB(0);
  stageA(1); stageB(1);
  stageA(2); stageB(2);
  __builtin_amdgcn_sched_barrier(0);
  asm volatile("s_waitcnt vmcnt(8)" ::: "memory");
  __builtin_amdgcn_s_barrier();
  __builtin_amdgcn_sched_barrier(0);

  const int fm32 = (lane & 15) * 32;   // fragment row * row-stride
  const int q8   = (lane >> 4) * 8;    // k-chunk within 32

  for (int t = 0; t < NT; ++t) {
    const int ab = (t & 3) * 8192 + wm * 32 + fm32 + q8;
    const int bb = 32768 + (t & 3) * 8192 + wn * 32 + fm32 + q8;
    const int tw = t + 3;              // wrap-staged by the lambdas

    bf16x8 bfr[4], af[4];
    // ================= phase A: rows wm..wm+63 =================
#pragma unroll
    for (int j = 0; j < 4; ++j) bfr[j] = *(const bf16x8*)&lds[bb + j * 512];
#pragma unroll
    for (int i = 0; i < 4; ++i) af[i] = *(const bf16x8*)&lds[ab + i * 512];
    stageA(tw);
    __builtin_amdgcn_sched_barrier(0);
    asm volatile("s_waitcnt lgkmcnt(0)" ::: "memory");
    __builtin_amdgcn_s_barrier();
    __builtin_amdgcn_sched_barrier(0);
    __builtin_amdgcn_s_setprio(1);
#pragma unroll
    for (int i = 0; i < 4; ++i)
#pragma unroll
      for (int j = 0; j < 4; ++j)
        acc[i][j] = __builtin_amdgcn_mfma_f32_16x16x32_bf16(
            af[i], bfr[j], acc[i][j], 0, 0, 0);
    __builtin_amdgcn_s_setprio(0);

    // ================= phase B: rows wm+64..wm+127 =================
#pragma unroll
    for (int i = 0; i < 4; ++i)
      af[i] = *(const bf16x8*)&lds[ab + 2048 + i * 512];
    stageB(tw);
    __builtin_amdgcn_sched_barrier(0);
    asm volatile("s_waitcnt vmcnt(8) lgkmcnt(0)" ::: "memory");  // t+1 landed
    __builtin_amdgcn_s_barrier();
    __builtin_amdgcn_sched_barrier(0);
    __builtin_amdgcn_s_setprio(1);
#pragma unroll
    for (int i = 0; i < 4; ++i)
#pragma unroll
      for (int j = 0; j < 4; ++j)
        acc[4 + i][j] = __builtin_amdgcn_mfma_f32_16x16x32_bf16(
            af[i], bfr[j], acc[4 + i][j], 0, 0, 0);
    __builtin_amdgcn_s_setprio(0);
  }

  // ---- epilogue: C/D layout col=lane&15, row=(lane>>4)*4+reg ----
  const int cr = (lane >> 4) * 4;
  const int cc = lane & 15;
#pragma unroll
  for (int i = 0; i < 8; ++i) {
#pragma unroll
    for (int j = 0; j < 4; ++j) {
#pragma unroll
      for (int r = 0; r < 4; ++r) {
        const int gm = bm * 256 + wm + i * 16 + cr + r;
        const int gn = bn * 256 + wn + j * 16 + cc;
        float v = acc[i][j][r];
        if constexpr (EPI == EPI_Q) {
          v += bias[gn];
          Cb[(size_t)gm * N + gn] = __float2bfloat16(v);
        } else if constexpr (EPI == EPI_K) {
          // gm = d, gn = global s. ekvT[b][1024+d][t] = exp(k)
          v = __expf(v + bias[gm]);
          const int b = gn >> 11, t = gn & (TT - 1);
          ekv[((size_t)b << 22) + (size_t)(1024 + gm) * TT + t] =
              __float2bfloat16(v);
        } else if constexpr (EPI == EPI_V) {
          // ekvT[b][d][t] = ek * v
          v += bias[gm];
          const int b = gn >> 11, t = gn & (TT - 1);
          const size_t base = ((size_t)b << 22);
          const float ek =
              __bfloat162float(ekv[base + (size_t)(1024 + gm) * TT + t]);
          ekv[base + (size_t)gm * TT + t] = __float2bfloat16(v * ek);
        } else if constexpr (EPI == EPI_ND) {
          Cb[(size_t)bz * strideCz + (size_t)gm * N + gn] =
              __float2bfloat16(v);
        } else if constexpr (EPI == EPI_MLP1) {
          v = fmaxf(v + bias[gn], 0.0f);
          Cb[(size_t)gm * N + gn] = __float2bfloat16(v);
        } else {  // EPI_MLP2: add == Cf aliasing is safe (read-then-write
          // of the same element within the same thread)
          v += bias[gn] + add[(size_t)gm * N + gn];
          Cf[(size_t)gm * N + gn] = v;
        }
      }
    }
  }
}

// ---------------------------------------------------------------------------
// Transpose + cast fp32 [K,N] -> bf16 [N,K] (LDS tiled)
// ---------------------------------------------------------------------------
__global__ __launch_bounds__(256)
void transpose_cast(const float* __restrict__ W, bf16* __restrict__ Wt,
                    int K, int N)
{
  __shared__ float tile[32][33];
  const int n0 = blockIdx.x * 32, k0 = blockIdx.y * 32;
  const int tx = threadIdx.x, ty = threadIdx.y;  // 32 x 8
#pragma unroll
  for (int i = 0; i < 32; i += 8)
    tile[ty + i][tx] = W[(size_t)(k0 + ty + i) * N + n0 + tx];
  __syncthreads();
#pragma unroll
  for (int i = 0; i < 32; i += 8)
    Wt[(size_t)(n0 + ty + i) * K + k0 + tx] =
        __float2bfloat16(tile[tx][ty + i]);
}

// ---------------------------------------------------------------------------
// ew = exp(pos_bias) as bf16 (global max cancels in num/den ratio)
// ---------------------------------------------------------------------------
__global__ __launch_bounds__(256)
void ew_kernel(const float* __restrict__ pb, bf16* __restrict__ ew)
{
  const size_t gid = (size_t)blockIdx.x * 256 + threadIdx.x;
  const float4 v = *(const float4*)(pb + gid * 4);
  union { bf16 h[4]; unsigned long long u; } pk;
  pk.h[0] = __float2bfloat16(__expf(v.x));
  pk.h[1] = __float2bfloat16(__expf(v.y));
  pk.h[2] = __float2bfloat16(__expf(v.z));
  pk.h[3] = __float2bfloat16(__expf(v.w));
  *(unsigned long long*)(ew + gid * 4) = pk.u;
}

// ---------------------------------------------------------------------------
// LayerNorm over D=1024, one block per row, output bf16
// ---------------------------------------------------------------------------
__global__ __launch_bounds__(256)
void ln_kernel(const float* __restrict__ x, const float* __restrict__ g,
               const float* __restrict__ b, bf16* __restrict__ out)
{
  const int row = blockIdx.x;
  const int tid = threadIdx.x;
  const float4 v = ((const float4*)(x + (size_t)row * DD))[tid];
  float s  = v.x + v.y + v.z + v.w;
  float s2 = v.x * v.x + v.y * v.y + v.z * v.z + v.w * v.w;
#pragma unroll
  for (int o = 32; o; o >>= 1) {
    s  += __shfl_down(s, o);
    s2 += __shfl_down(s2, o);
  }
  __shared__ float red[8];
  if ((tid & 63) == 0) { red[tid >> 6] = s; red[4 + (tid >> 6)] = s2; }
  __syncthreads();
  const float ts  = red[0] + red[1] + red[2] + red[3];
  const float ts2 = red[4] + red[5] + red[6] + red[7];
  const float mu = ts * (1.0f / DD);
  const float rs = rsqrtf(ts2 * (1.0f / DD) - mu * mu + 1e-5f);
  const float4 gv = ((const float4*)g)[tid];
  const float4 bv = ((const float4*)b)[tid];
  union { bf16 h[4]; unsigned long long u; } pk;
  pk.h[0] = __float2bfloat16((v.x - mu) * rs * gv.x + bv.x);
  pk.h[1] = __float2bfloat16((v.y - mu) * rs * gv.y + bv.y);
  pk.h[2] = __float2bfloat16((v.z - mu) * rs * gv.z + bv.z);
  pk.h[3] = __float2bfloat16((v.w - mu) * rs * gv.w + bv.w);
  ((unsigned long long*)(out + (size_t)row * DD))[tid] = pk.u;
}

// ---------------------------------------------------------------------------
// Fused: x2 = sigmoid(q) * num/den + x  (x2 aliases d_out), then
// h2 = LN(x2, g2, b2) -> hout bf16.  One block per row.
// ---------------------------------------------------------------------------
__global__ __launch_bounds__(256)
void combine_ln_kernel(const bf16* __restrict__ q, const bf16* __restrict__ nd,
                       const float* __restrict__ x,
                       const float* __restrict__ g, const float* __restrict__ b,
                       float* __restrict__ x2, bf16* __restrict__ hout)
{
  const int row = blockIdx.x;
  const int tid = threadIdx.x;
  const int c = tid * 4;
  const bf16* ndr = nd + (size_t)row * 2048;
  union { unsigned long long u; bf16 h[4]; } un, ud, uq;
  un.u = *(const unsigned long long*)(ndr + c);
  ud.u = *(const unsigned long long*)(ndr + 1024 + c);
  uq.u = *(const unsigned long long*)(q + (size_t)row * DD + c);
  const float4 xv = *(const float4*)(x + (size_t)row * DD + c);
  float4 o;
  o.x = xv.x + (__bfloat162float(un.h[0]) / __bfloat162float(ud.h[0])) /
                   (1.0f + __expf(-__bfloat162float(uq.h[0])));
  o.y = xv.y + (__bfloat162float(un.h[1]) / __bfloat162float(ud.h[1])) /
                   (1.0f + __expf(-__bfloat162float(uq.h[1])));
  o.z = xv.z + (__bfloat162float(un.h[2]) / __bfloat162float(ud.h[2])) /
                   (1.0f + __expf(-__bfloat162float(uq.h[2])));
  o.w = xv.w + (__bfloat162float(un.h[3]) / __bfloat162float(ud.h[3])) /
                   (1.0f + __expf(-__bfloat162float(uq.h[3])));
  *(float4*)(x2 + (size_t)row * DD + c) = o;

  // ---- LayerNorm of o across the row ----
  float s  = o.x + o.y + o.z + o.w;
  float s2 = o.x * o.x + o.y * o.y + o.z * o.z + o.w * o.w;
#pragma unroll
  for (int off = 32; off; off >>= 1) {
    s  += __shfl_down(s, off);
    s2 += __shfl_down(s2, off);
  }
  __shared__ float red[8];
  if ((tid & 63) == 0) { red[tid >> 6] = s; red[4 + (tid >> 6)] = s2; }
  __syncthreads();
  const float ts  = red[0] + red[1] + red[2] + red[3];
  const float ts2 = red[4] + red[5] + red[6] + red[7];
  const float mu = ts * (1.0f / DD);
  const float rs = rsqrtf(ts2 * (1.0f / DD) - mu * mu + 1e-5f);
  const float4 gv = ((const float4*)g)[tid];
  const float4 bv = ((const float4*)b)[tid];
  union { bf16 h[4]; unsigned long long u; } pk;
  pk.h[0] = __float2bfloat16((o.x - mu) * rs * gv.x + bv.x);
  pk.h[1] = __float2bfloat16((o.y - mu) * rs * gv.y + bv.y);
  pk.h[2] = __float2bfloat16((o.z - mu) * rs * gv.z + bv.z);
  pk.h[3] = __float2bfloat16((o.w - mu) * rs * gv.w + bv.w);
  ((unsigned long long*)(hout + (size_t)row * DD))[tid] = pk.u;
}

// ---------------------------------------------------------------------------
extern "C" void kernel_launch(void* const* d_in, const int* in_sizes, int n_in,
                              void* d_out, int out_size, void* d_ws,
                              size_t ws_size, hipStream_t stream)
{
  (void)in_sizes; (void)n_in; (void)out_size; (void)ws_size;
  const float* x   = (const float*)d_in[0];
  const float* Wq  = (const float*)d_in[1];
  const float* bq  = (const float*)d_in[2];
  const float* Wk  = (const float*)d_in[3];
  const float* bk  = (const float*)d_in[4];
  const float* Wv  = (const float*)d_in[5];
  const float* bv  = (const float*)d_in[6];
  const float* pb  = (const float*)d_in[7];
  const float* g1  = (const float*)d_in[8];
  const float* be1 = (const float*)d_in[9];
  const float* W1  = (const float*)d_in[10];
  const float* bm1 = (const float*)d_in[11];
  const float* W2  = (const float*)d_in[12];
  const float* bm2 = (const float*)d_in[13];
  const float* g2  = (const float*)d_in[14];
  const float* be2 = (const float*)d_in[15];
  float* out = (float*)d_out;

  // ---- workspace layout: 222 MiB total ----
  const size_t MiB = 1024 * 1024;
  char* w = (char*)d_ws;
  bf16* hbf = (bf16*)w;  w += (size_t)MM * DD * 2;        // 32 MiB (h, then h2)
  bf16* wqt = (bf16*)w;  w += (size_t)DD * DD * 2;        // 2 MiB
  bf16* wkt = (bf16*)w;  w += (size_t)DD * DD * 2;
  bf16* wvt = (bf16*)w;  w += (size_t)DD * DD * 2;
  bf16* w1t = (bf16*)w;  w += (size_t)4096 * DD * 2;      // 8 MiB
  bf16* w2t = (bf16*)w;  w += (size_t)DD * 4096 * 2;      // 8 MiB
  // scratch region (168 MiB), fully dead after combine_ln_kernel:
  char* scr = w;
  bf16* qbf = (bf16*)scr;                                  // 32 MiB
  bf16* ewb = (bf16*)(scr + 32 * MiB);                     // 8 MiB
  bf16* ekv = (bf16*)(scr + 40 * MiB);   // 64 MiB [b][2048: 0..1023=ek*v, 1024..2047=ek][t]
  bf16* nd  = (bf16*)(scr + 104 * MiB);  // 64 MiB [b][t][2048: num|den]
  bf16* mid = (bf16*)scr;                // 128 MiB, overlays scratch after combine
  float* x2 = out;                       // alias: residual lives in d_out

  const dim3 tb(32, 8);
  transpose_cast<<<dim3(DD / 32, DD / 32), tb, 0, stream>>>(Wq, wqt, DD, DD);
  transpose_cast<<<dim3(DD / 32, DD / 32), tb, 0, stream>>>(Wk, wkt, DD, DD);
  transpose_cast<<<dim3(DD / 32, DD / 32), tb, 0, stream>>>(Wv, wvt, DD, DD);
  transpose_cast<<<dim3(4096 / 32, DD / 32), tb, 0, stream>>>(W1, w1t, DD, 4096);
  transpose_cast<<<dim3(DD / 32, 4096 / 32), tb, 0, stream>>>(W2, w2t, 4096, DD);

  ew_kernel<<<(TT * TT / 4) / 256, 256, 0, stream>>>(pb, ewb);
  ln_kernel<<<MM, 256, 0, stream>>>(x, g1, be1, hbf);

  // q = h @ Wq + bq  -> qbf [16384,1024] bf16
  gemm_bt<EPI_Q><<<(MM / 256) * (DD / 256), 512, 0, stream>>>(
      hbf, wqt, MM, DD, DD, 0, 0, nullptr, qbf, 0, bq, nullptr, nullptr);
  // ek^T: C[d, s] = Wkt @ h^T, epilogue exp -> ekv rows 1024..2047
  gemm_bt<EPI_K><<<(DD / 256) * (MM / 256), 512, 0, stream>>>(
      wkt, hbf, DD, MM, DD, 0, 0, nullptr, nullptr, 0, bk, nullptr, ekv);
  // v^T: epilogue *ek -> ekv rows 0..1023
  gemm_bt<EPI_V><<<(DD / 256) * (MM / 256), 512, 0, stream>>>(
      wvt, hbf, DD, MM, DD, 0, 0, nullptr, nullptr, 0, bv, nullptr, ekv);
  // nd[b] = ew @ ekv[b]^T : [2048,2048] bf16 per batch (XCD = batch)
  gemm_bt<EPI_ND><<<BB * (TT / 256) * (TT / 256), 512, 0, stream>>>(
      ewb, ekv, TT, TT, TT, 0, (long long)TT * TT, nullptr, nd,
      (long long)TT * TT, nullptr, nullptr, nullptr);

  // fused: x2 = sigmoid(q)*num/den + x ; hbf = LN(x2)
  combine_ln_kernel<<<MM, 256, 0, stream>>>(qbf, nd, x, g2, be2, x2, hbf);

  // mid = relu(h2 @ W1 + b1) bf16 [16384,4096]
  gemm_bt<EPI_MLP1><<<(MM / 256) * (4096 / 256), 512, 0, stream>>>(
      hbf, w1t, MM, 4096, DD, 0, 0, nullptr, mid, 0, bm1, nullptr, nullptr);
  // out = mid @ W2 + b2 + x2 fp32 [16384,1024]  (add == Cf, safe)
  gemm_bt<EPI_MLP2><<<(MM / 256) * (DD / 256), 512, 0, stream>>>(
      mid, w2t, MM, DD, 4096, 0, 0, out, nullptr, 0, bm2, x2, nullptr);
}

// Round 3
// 751.704 us; speedup vs baseline: 1.0526x; 1.0123x over previous
//
#include <hip/hip_runtime.h>
#include <hip/hip_bf16.h>
#include <stdint.h>

typedef __hip_bfloat16 bf16;
typedef __attribute__((ext_vector_type(4))) float f32x4;
typedef __attribute__((ext_vector_type(8))) short bf16x8;

// Problem constants
#define BB   8
#define TT   2048
#define DD   1024
#define MM   (BB * TT)   // 16384 rows

enum { EPI_Q = 0, EPI_K, EPI_V, EPI_ND, EPI_MLP1, EPI_MLP2 };

static __device__ __forceinline__ void async_ld16(const bf16* g, bf16* l) {
  __builtin_amdgcn_global_load_lds(
      (const __attribute__((address_space(1))) void*)g,
      (__attribute__((address_space(3))) void*)l, 16, 0, 0);
}

// ---------------------------------------------------------------------------
// Universal GEMM: C[M,N] = A[M,K] @ B[N,K]^T, A/B bf16 row-major (K inner).
//
// 256x256 tile, BK=32, 512 threads (8 waves as 2Mx4N, each owning 128x64).
// Deep pipeline: 4 LDS buffers (4 x (A 16KB + B 16KB) = 128 KiB); during
// K-tile t we stage K-tile t+3 into buf[(t+3)&3] == buf[(t-1)&3].  All
// ds_reads of that buffer completed before the tile t-1 phase-B barrier
// (every wave executes lgkmcnt(0) before it), and the stage is issued
// after that barrier -> race-free without region phasing.  vmcnt(8) once
// per K-tile (phase B) keeps 2 K-tiles of global_load_lds in flight
// ACROSS barriers (T3+T4); raw s_barrier (no vmcnt(0) drain); lgkmcnt(0)
// before each barrier; setprio(1) around each 16-MFMA cluster (T5).
// Wrap-staging keeps exactly 4 loads/tile issued so the counted-vmcnt
// arithmetic stays uniform through the tail.
//
// LDS bank swizzle (T2, round-2 fix): rows are 32 bf16 = 4 x 16B chunks.
// Un-swizzled, a wave quarter (16 lanes) reads 16 rows at 64B stride ->
// even rows hit banks 0-3, odd rows banks 16-19 = 8-way conflict
// (measured 12.6M conflict-cycles/dispatch).  We store global chunk
// s ^ c(r) in LDS slot s, c(r) = (r>>1)&3, by permuting the PER-LANE
// GLOBAL SOURCE column (LDS dest stays linear, as global_load_lds
// requires) and reading slot (lane>>4) ^ ((lane>>1)&3).  Each quarter
// then spreads over all 8 four-bank groups, 2 lanes/group = free (m136).
// c is invariant across all fragment-block offsets (multiples of 16
// rows), so the read XOR folds into the lane-constant base.
//
// Grid is 1-D with bijective XCD swizzle (all nwg % 8 == 0). EPI_ND decodes
// batch from the top bits -> each XCD owns one batch (ew panel L2 reuse).
// Requires: M,N % 256 == 0; K % 32 == 0; K/32 a power of two >= 4.
// ---------------------------------------------------------------------------
template<int EPI>
__global__ __launch_bounds__(512, 2)
void gemm_bt(const bf16* __restrict__ A, const bf16* __restrict__ B,
             int M, int N, int K,
             long long strideAz, long long strideBz,
             float* __restrict__ Cf,
             bf16* __restrict__ Cb, long long strideCz,
             const float* __restrict__ bias,
             const float* __restrict__ add,
             bf16* __restrict__ ekv)
{
  (void)M;
  // A region: [0, 32768) elements (4 buffers x 8192), B: [32768, 65536)
  __shared__ __align__(16) bf16 lds[65536];

  const int tid  = threadIdx.x;
  const int wave = tid >> 6;
  const int lane = tid & 63;

  // ---- XCD-aware swizzle on 1-D grid (nwg % 8 == 0 for every launch) ----
  const int nwg = (int)gridDim.x;
  const int bid = (int)blockIdx.x;
  const int swz = (bid & 7) * (nwg >> 3) + (bid >> 3);
  int bn, bm, bz;
  if constexpr (EPI == EPI_ND) {       // batch = XCD
    bn = swz & 7; bm = (swz >> 3) & 7; bz = swz >> 6;
  } else {
    const int nbn = N >> 8;            // power of two (4 / 16 / 64)
    const int lnb = 31 - __clz(nbn);
    bn = swz & (nbn - 1); bm = swz >> lnb; bz = 0;
  }
  A += (size_t)bz * strideAz;
  B += (size_t)bz * strideBz;

  const int wm = (wave >> 2) * 128;    // wave's M offset in tile
  const int wn = (wave & 3) * 64;      // wave's N offset in tile

  // ---- staging addressing: per K-tile each thread issues 2 A + 2 B loads.
  // lane l -> row (wave*32 + (l>>2)); SOURCE chunk is bank-swizzled:
  // (l&3) ^ c(row), c(row) = (row>>1)&3 = (l>>3)&3 (wave-invariant).
  // LDS dest is the wave-uniform segment base + lane*16 (linear, HW rule).
  const int lr = lane >> 2;            // 0..15
  const int lc = (((lane & 3) ^ ((lane >> 3) & 3))) * 8;  // swizzled src col
  const bf16* Ag0 = A + ((size_t)bm * 256 + wave * 32 + lr) * K + lc;
  const bf16* Bg0 = B + ((size_t)bn * 256 + wave * 32 + lr) * K + lc;
  const size_t K16 = (size_t)16 * K;   // 16 rows
  const int ldsAW = wave * 1024;       // wave's segment (elements)
  const int ldsBW = 32768 + wave * 1024;
  const int NT = K >> 5;               // number of K-tiles (pow2, >= 4)

  auto stageA = [&](int tt) {
    const int bo = (tt & 3) * 8192;
    const bf16* g = Ag0 + (size_t)(tt & (NT - 1)) * 32;
    async_ld16(g,       &lds[bo + ldsAW]);
    async_ld16(g + K16, &lds[bo + ldsAW + 512]);
  };
  auto stageB = [&](int tt) {
    const int bo = (tt & 3) * 8192;
    const bf16* g = Bg0 + (size_t)(tt & (NT - 1)) * 32;
    async_ld16(g,       &lds[bo + ldsBW]);
    async_ld16(g + K16, &lds[bo + ldsBW + 512]);
  };

  f32x4 acc[8][4];
#pragma unroll
  for (int i = 0; i < 8; ++i)
#pragma unroll
    for (int j = 0; j < 4; ++j) acc[i][j] = {0.f, 0.f, 0.f, 0.f};

  // ---- prologue: stage K-tiles 0,1,2; wait tile 0 (8 newer may fly) ----
  stageA(0); stageB(0);
  stageA(1); stageB(1);
  stageA(2); stageB(2);
  __builtin_amdgcn_sched_barrier(0);
  asm volatile("s_waitcnt vmcnt(8)" ::: "memory");
  __builtin_amdgcn_s_barrier();
  __builtin_amdgcn_sched_barrier(0);

  const int fm32 = (lane & 15) * 32;   // fragment row * row-stride
  // read slot = (lane>>4) ^ c(row); c = (lane>>1)&3 for row==fm (mod 16)
  const int qs = (((lane >> 4) ^ ((lane >> 1) & 3))) * 8;

  for (int t = 0; t < NT; ++t) {
    const int ab = (t & 3) * 8192 + wm * 32 + fm32 + qs;
    const int bb = 32768 + (t & 3) * 8192 + wn * 32 + fm32 + qs;
    const int tw = t + 3;              // wrap-staged by the lambdas

    bf16x8 bfr[4], af[4];
    // ================= phase A: rows wm..wm+63 =================
#pragma unroll
    for (int j = 0; j < 4; ++j) bfr[j] = *(const bf16x8*)&lds[bb + j * 512];
#pragma unroll
    for (int i = 0; i < 4; ++i) af[i] = *(const bf16x8*)&lds[ab + i * 512];
    stageA(tw);
    __builtin_amdgcn_sched_barrier(0);
    asm volatile("s_waitcnt lgkmcnt(0)" ::: "memory");
    __builtin_amdgcn_s_barrier();
    __builtin_amdgcn_sched_barrier(0);
    __builtin_amdgcn_s_setprio(1);
#pragma unroll
    for (int i = 0; i < 4; ++i)
#pragma unroll
      for (int j = 0; j < 4; ++j)
        acc[i][j] = __builtin_amdgcn_mfma_f32_16x16x32_bf16(
            af[i], bfr[j], acc[i][j], 0, 0, 0);
    __builtin_amdgcn_s_setprio(0);

    // ================= phase B: rows wm+64..wm+127 =================
#pragma unroll
    for (int i = 0; i < 4; ++i)
      af[i] = *(const bf16x8*)&lds[ab + 2048 + i * 512];
    stageB(tw);
    __builtin_amdgcn_sched_barrier(0);
    asm volatile("s_waitcnt vmcnt(8) lgkmcnt(0)" ::: "memory");  // t+1 landed
    __builtin_amdgcn_s_barrier();
    __builtin_amdgcn_sched_barrier(0);
    __builtin_amdgcn_s_setprio(1);
#pragma unroll
    for (int i = 0; i < 4; ++i)
#pragma unroll
      for (int j = 0; j < 4; ++j)
        acc[4 + i][j] = __builtin_amdgcn_mfma_f32_16x16x32_bf16(
            af[i], bfr[j], acc[4 + i][j], 0, 0, 0);
    __builtin_amdgcn_s_setprio(0);
  }

  // ---- epilogue: C/D layout col=lane&15, row=(lane>>4)*4+reg ----
  const int cr = (lane >> 4) * 4;
  const int cc = lane & 15;
#pragma unroll
  for (int i = 0; i < 8; ++i) {
#pragma unroll
    for (int j = 0; j < 4; ++j) {
#pragma unroll
      for (int r = 0; r < 4; ++r) {
        const int gm = bm * 256 + wm + i * 16 + cr + r;
        const int gn = bn * 256 + wn + j * 16 + cc;
        float v = acc[i][j][r];
        if constexpr (EPI == EPI_Q) {
          v += bias[gn];
          Cb[(size_t)gm * N + gn] = __float2bfloat16(v);
        } else if constexpr (EPI == EPI_K) {
          // gm = d, gn = global s. ekvT[b][1024+d][t] = exp(k)
          v = __expf(v + bias[gm]);
          const int b = gn >> 11, t = gn & (TT - 1);
          ekv[((size_t)b << 22) + (size_t)(1024 + gm) * TT + t] =
              __float2bfloat16(v);
        } else if constexpr (EPI == EPI_V) {
          // ekvT[b][d][t] = ek * v
          v += bias[gm];
          const int b = gn >> 11, t = gn & (TT - 1);
          const size_t base = ((size_t)b << 22);
          const float ek =
              __bfloat162float(ekv[base + (size_t)(1024 + gm) * TT + t]);
          ekv[base + (size_t)gm * TT + t] = __float2bfloat16(v * ek);
        } else if constexpr (EPI == EPI_ND) {
          Cb[(size_t)bz * strideCz + (size_t)gm * N + gn] =
              __float2bfloat16(v);
        } else if constexpr (EPI == EPI_MLP1) {
          v = fmaxf(v + bias[gn], 0.0f);
          Cb[(size_t)gm * N + gn] = __float2bfloat16(v);
        } else {  // EPI_MLP2: add == Cf aliasing is safe (read-then-write
          // of the same element within the same thread)
          v += bias[gn] + add[(size_t)gm * N + gn];
          Cf[(size_t)gm * N + gn] = v;
        }
      }
    }
  }
}

// ---------------------------------------------------------------------------
// Transpose + cast fp32 [K,N] -> bf16 [N,K] (LDS tiled)
// ---------------------------------------------------------------------------
__global__ __launch_bounds__(256)
void transpose_cast(const float* __restrict__ W, bf16* __restrict__ Wt,
                    int K, int N)
{
  __shared__ float tile[32][33];
  const int n0 = blockIdx.x * 32, k0 = blockIdx.y * 32;
  const int tx = threadIdx.x, ty = threadIdx.y;  // 32 x 8
#pragma unroll
  for (int i = 0; i < 32; i += 8)
    tile[ty + i][tx] = W[(size_t)(k0 + ty + i) * N + n0 + tx];
  __syncthreads();
#pragma unroll
  for (int i = 0; i < 32; i += 8)
    Wt[(size_t)(n0 + ty + i) * K + k0 + tx] =
        __float2bfloat16(tile[tx][ty + i]);
}

// ---------------------------------------------------------------------------
// ew = exp(pos_bias) as bf16 (global max cancels in num/den ratio)
// ---------------------------------------------------------------------------
__global__ __launch_bounds__(256)
void ew_kernel(const float* __restrict__ pb, bf16* __restrict__ ew)
{
  const size_t gid = (size_t)blockIdx.x * 256 + threadIdx.x;
  const float4 v = *(const float4*)(pb + gid * 4);
  union { bf16 h[4]; unsigned long long u; } pk;
  pk.h[0] = __float2bfloat16(__expf(v.x));
  pk.h[1] = __float2bfloat16(__expf(v.y));
  pk.h[2] = __float2bfloat16(__expf(v.z));
  pk.h[3] = __float2bfloat16(__expf(v.w));
  *(unsigned long long*)(ew + gid * 4) = pk.u;
}

// ---------------------------------------------------------------------------
// LayerNorm over D=1024, one block per row, output bf16
// ---------------------------------------------------------------------------
__global__ __launch_bounds__(256)
void ln_kernel(const float* __restrict__ x, const float* __restrict__ g,
               const float* __restrict__ b, bf16* __restrict__ out)
{
  const int row = blockIdx.x;
  const int tid = threadIdx.x;
  const float4 v = ((const float4*)(x + (size_t)row * DD))[tid];
  float s  = v.x + v.y + v.z + v.w;
  float s2 = v.x * v.x + v.y * v.y + v.z * v.z + v.w * v.w;
#pragma unroll
  for (int o = 32; o; o >>= 1) {
    s  += __shfl_down(s, o);
    s2 += __shfl_down(s2, o);
  }
  __shared__ float red[8];
  if ((tid & 63) == 0) { red[tid >> 6] = s; red[4 + (tid >> 6)] = s2; }
  __syncthreads();
  const float ts  = red[0] + red[1] + red[2] + red[3];
  const float ts2 = red[4] + red[5] + red[6] + red[7];
  const float mu = ts * (1.0f / DD);
  const float rs = rsqrtf(ts2 * (1.0f / DD) - mu * mu + 1e-5f);
  const float4 gv = ((const float4*)g)[tid];
  const float4 bv = ((const float4*)b)[tid];
  union { bf16 h[4]; unsigned long long u; } pk;
  pk.h[0] = __float2bfloat16((v.x - mu) * rs * gv.x + bv.x);
  pk.h[1] = __float2bfloat16((v.y - mu) * rs * gv.y + bv.y);
  pk.h[2] = __float2bfloat16((v.z - mu) * rs * gv.z + bv.z);
  pk.h[3] = __float2bfloat16((v.w - mu) * rs * gv.w + bv.w);
  ((unsigned long long*)(out + (size_t)row * DD))[tid] = pk.u;
}

// ---------------------------------------------------------------------------
// Fused: x2 = sigmoid(q) * num/den + x  (x2 aliases d_out), then
// h2 = LN(x2, g2, b2) -> hout bf16.  One block per row.
// ---------------------------------------------------------------------------
__global__ __launch_bounds__(256)
void combine_ln_kernel(const bf16* __restrict__ q, const bf16* __restrict__ nd,
                       const float* __restrict__ x,
                       const float* __restrict__ g, const float* __restrict__ b,
                       float* __restrict__ x2, bf16* __restrict__ hout)
{
  const int row = blockIdx.x;
  const int tid = threadIdx.x;
  const int c = tid * 4;
  const bf16* ndr = nd + (size_t)row * 2048;
  union { unsigned long long u; bf16 h[4]; } un, ud, uq;
  un.u = *(const unsigned long long*)(ndr + c);
  ud.u = *(const unsigned long long*)(ndr + 1024 + c);
  uq.u = *(const unsigned long long*)(q + (size_t)row * DD + c);
  const float4 xv = *(const float4*)(x + (size_t)row * DD + c);
  float4 o;
  o.x = xv.x + (__bfloat162float(un.h[0]) / __bfloat162float(ud.h[0])) /
                   (1.0f + __expf(-__bfloat162float(uq.h[0])));
  o.y = xv.y + (__bfloat162float(un.h[1]) / __bfloat162float(ud.h[1])) /
                   (1.0f + __expf(-__bfloat162float(uq.h[1])));
  o.z = xv.z + (__bfloat162float(un.h[2]) / __bfloat162float(ud.h[2])) /
                   (1.0f + __expf(-__bfloat162float(uq.h[2])));
  o.w = xv.w + (__bfloat162float(un.h[3]) / __bfloat162float(ud.h[3])) /
                   (1.0f + __expf(-__bfloat162float(uq.h[3])));
  *(float4*)(x2 + (size_t)row * DD + c) = o;

  // ---- LayerNorm of o across the row ----
  float s  = o.x + o.y + o.z + o.w;
  float s2 = o.x * o.x + o.y * o.y + o.z * o.z + o.w * o.w;
#pragma unroll
  for (int off = 32; off; off >>= 1) {
    s  += __shfl_down(s, off);
    s2 += __shfl_down(s2, off);
  }
  __shared__ float red[8];
  if ((tid & 63) == 0) { red[tid >> 6] = s; red[4 + (tid >> 6)] = s2; }
  __syncthreads();
  const float ts  = red[0] + red[1] + red[2] + red[3];
  const float ts2 = red[4] + red[5] + red[6] + red[7];
  const float mu = ts * (1.0f / DD);
  const float rs = rsqrtf(ts2 * (1.0f / DD) - mu * mu + 1e-5f);
  const float4 gv = ((const float4*)g)[tid];
  const float4 bv = ((const float4*)b)[tid];
  union { bf16 h[4]; unsigned long long u; } pk;
  pk.h[0] = __float2bfloat16((o.x - mu) * rs * gv.x + bv.x);
  pk.h[1] = __float2bfloat16((o.y - mu) * rs * gv.y + bv.y);
  pk.h[2] = __float2bfloat16((o.z - mu) * rs * gv.z + bv.z);
  pk.h[3] = __float2bfloat16((o.w - mu) * rs * gv.w + bv.w);
  ((unsigned long long*)(hout + (size_t)row * DD))[tid] = pk.u;
}

// ---------------------------------------------------------------------------
extern "C" void kernel_launch(void* const* d_in, const int* in_sizes, int n_in,
                              void* d_out, int out_size, void* d_ws,
                              size_t ws_size, hipStream_t stream)
{
  (void)in_sizes; (void)n_in; (void)out_size; (void)ws_size;
  const float* x   = (const float*)d_in[0];
  const float* Wq  = (const float*)d_in[1];
  const float* bq  = (const float*)d_in[2];
  const float* Wk  = (const float*)d_in[3];
  const float* bk  = (const float*)d_in[4];
  const float* Wv  = (const float*)d_in[5];
  const float* bv  = (const float*)d_in[6];
  const float* pb  = (const float*)d_in[7];
  const float* g1  = (const float*)d_in[8];
  const float* be1 = (const float*)d_in[9];
  const float* W1  = (const float*)d_in[10];
  const float* bm1 = (const float*)d_in[11];
  const float* W2  = (const float*)d_in[12];
  const float* bm2 = (const float*)d_in[13];
  const float* g2  = (const float*)d_in[14];
  const float* be2 = (const float*)d_in[15];
  float* out = (float*)d_out;

  // ---- workspace layout: 222 MiB total ----
  const size_t MiB = 1024 * 1024;
  char* w = (char*)d_ws;
  bf16* hbf = (bf16*)w;  w += (size_t)MM * DD * 2;        // 32 MiB (h, then h2)
  bf16* wqt = (bf16*)w;  w += (size_t)DD * DD * 2;        // 2 MiB
  bf16* wkt = (bf16*)w;  w += (size_t)DD * DD * 2;
  bf16* wvt = (bf16*)w;  w += (size_t)DD * DD * 2;
  bf16* w1t = (bf16*)w;  w += (size_t)4096 * DD * 2;      // 8 MiB
  bf16* w2t = (bf16*)w;  w += (size_t)DD * 4096 * 2;      // 8 MiB
  // scratch region (168 MiB), fully dead after combine_ln_kernel:
  char* scr = w;
  bf16* qbf = (bf16*)scr;                                  // 32 MiB
  bf16* ewb = (bf16*)(scr + 32 * MiB);                     // 8 MiB
  bf16* ekv = (bf16*)(scr + 40 * MiB);   // 64 MiB [b][2048: 0..1023=ek*v, 1024..2047=ek][t]
  bf16* nd  = (bf16*)(scr + 104 * MiB);  // 64 MiB [b][t][2048: num|den]
  bf16* mid = (bf16*)scr;                // 128 MiB, overlays scratch after combine
  float* x2 = out;                       // alias: residual lives in d_out

  const dim3 tb(32, 8);
  transpose_cast<<<dim3(DD / 32, DD / 32), tb, 0, stream>>>(Wq, wqt, DD, DD);
  transpose_cast<<<dim3(DD / 32, DD / 32), tb, 0, stream>>>(Wk, wkt, DD, DD);
  transpose_cast<<<dim3(DD / 32, DD / 32), tb, 0, stream>>>(Wv, wvt, DD, DD);
  transpose_cast<<<dim3(4096 / 32, DD / 32), tb, 0, stream>>>(W1, w1t, DD, 4096);
  transpose_cast<<<dim3(DD / 32, 4096 / 32), tb, 0, stream>>>(W2, w2t, 4096, DD);

  ew_kernel<<<(TT * TT / 4) / 256, 256, 0, stream>>>(pb, ewb);
  ln_kernel<<<MM, 256, 0, stream>>>(x, g1, be1, hbf);

  // q = h @ Wq + bq  -> qbf [16384,1024] bf16
  gemm_bt<EPI_Q><<<(MM / 256) * (DD / 256), 512, 0, stream>>>(
      hbf, wqt, MM, DD, DD, 0, 0, nullptr, qbf, 0, bq, nullptr, nullptr);
  // ek^T: C[d, s] = Wkt @ h^T, epilogue exp -> ekv rows 1024..2047
  gemm_bt<EPI_K><<<(DD / 256) * (MM / 256), 512, 0, stream>>>(
      wkt, hbf, DD, MM, DD, 0, 0, nullptr, nullptr, 0, bk, nullptr, ekv);
  // v^T: epilogue *ek -> ekv rows 0..1023
  gemm_bt<EPI_V><<<(DD / 256) * (MM / 256), 512, 0, stream>>>(
      wvt, hbf, DD, MM, DD, 0, 0, nullptr, nullptr, 0, bv, nullptr, ekv);
  // nd[b] = ew @ ekv[b]^T : [2048,2048] bf16 per batch (XCD = batch)
  gemm_bt<EPI_ND><<<BB * (TT / 256) * (TT / 256), 512, 0, stream>>>(
      ewb, ekv, TT, TT, TT, 0, (long long)TT * TT, nullptr, nd,
      (long long)TT * TT, nullptr, nullptr, nullptr);

  // fused: x2 = sigmoid(q)*num/den + x ; hbf = LN(x2)
  combine_ln_kernel<<<MM, 256, 0, stream>>>(qbf, nd, x, g2, be2, x2, hbf);

  // mid = relu(h2 @ W1 + b1) bf16 [16384,4096]
  gemm_bt<EPI_MLP1><<<(MM / 256) * (4096 / 256), 512, 0, stream>>>(
      hbf, w1t, MM, 4096, DD, 0, 0, nullptr, mid, 0, bm1, nullptr, nullptr);
  // out = mid @ W2 + b2 + x2 fp32 [16384,1024]  (add == Cf, safe)
  gemm_bt<EPI_MLP2><<<(MM / 256) * (DD / 256), 512, 0, stream>>>(
      mid, w2t, MM, DD, 4096, 0, 0, out, nullptr, 0, bm2, x2, nullptr);
}

// Round 5
// 732.018 us; speedup vs baseline: 1.0809x; 1.0269x over previous
//
#include <hip/hip_runtime.h>
#include <hip/hip_bf16.h>
#include <stdint.h>

typedef __hip_bfloat16 bf16;
typedef __attribute__((ext_vector_type(4))) float f32x4;
typedef __attribute__((ext_vector_type(8))) short bf16x8;

// Problem constants
#define BB   8
#define TT   2048
#define DD   1024
#define MM   (BB * TT)   // 16384 rows

enum { EPI_Q = 0, EPI_K, EPI_V, EPI_ND, EPI_MLP1, EPI_MLP2 };

static __device__ __forceinline__ void async_ld16(const bf16* g, bf16* l) {
  __builtin_amdgcn_global_load_lds(
      (const __attribute__((address_space(1))) void*)g,
      (__attribute__((address_space(3))) void*)l, 16, 0, 0);
}

// ---------------------------------------------------------------------------
// Universal GEMM: C[M,N] = A[M,K] @ B[N,K]^T, A/B bf16 row-major (K inner).
//
// 256x256 tile, BK=32, 512 threads (8 waves as 2Mx4N, each owning 128x64).
// Deep pipeline: 4 LDS buffers (128 KiB); during K-tile t we stage K-tile
// t+3 into buf[(t+3)&3] == buf[(t-1)&3], whose reads all retired before
// the preceding barrier (counted lgkm waits below).  vmcnt(6) once per
// K-tile keeps 3 stage-calls in flight ACROSS barriers (T3+T4) and
// guarantees tile t+1 fully landed (all waves) before its reads are
// issued after the phase-A barrier.
//
// Fine interleave (T3): fragment ds_reads are issued ONE PHASE AHEAD so
// they fly UNDER the MFMA cluster instead of serializing before it
// (round-3 measured: serial reads+MFMA = 768+621 cyc/phase/CU ->
// MfmaUtil 41%).  Counted waits (DS-only lgkm queue, in-order):
//   phase A: issue afB_t(4) reads; vmcnt(6) lgkm(4) retires bfr_t/afA_t
//            (issued last phase); MFMA A overlaps afB_t reads; barrier.
//   phase B: issue bfrX/afA_{t+1}(8) reads; lgkm(8) retires afB_t;
//            MFMA B overlaps next-tile reads; barrier.
// Register discipline: only bfr is ping-ponged (bfrC consumed by BOTH
// phase MFMAs of tile t while bfrX loads); afA is consumed in phase A
// only, so phase B may overwrite it in place.  4 frag sets + acc ~= 215
// VGPR -- under the 256 cliff, no spills to perturb counted waits.
//
// LDS bank swizzle (T2, verified 0 conflicts in round 3): store global
// 16B chunk s ^ ((row>>1)&3) in LDS slot s by permuting the PER-LANE
// GLOBAL SOURCE column (LDS dest stays linear, as global_load_lds
// requires); read slot (lane>>4) ^ ((lane>>1)&3).
//
// Grid is 1-D with bijective XCD swizzle (all nwg % 8 == 0). EPI_ND decodes
// batch = XCD.  Requires: M,N % 256 == 0; K % 32 == 0; K/32 even pow2 >= 4.
// ---------------------------------------------------------------------------
template<int EPI>
__global__ __launch_bounds__(512, 2)
void gemm_bt(const bf16* __restrict__ A, const bf16* __restrict__ B,
             int M, int N, int K,
             long long strideAz, long long strideBz,
             float* __restrict__ Cf,
             bf16* __restrict__ Cb, long long strideCz,
             const float* __restrict__ bias,
             const float* __restrict__ add,
             bf16* __restrict__ ekv)
{
  (void)M;
  // A region: [0, 32768) elements (4 buffers x 8192), B: [32768, 65536)
  __shared__ __align__(16) bf16 lds[65536];

  const int tid  = threadIdx.x;
  const int wave = tid >> 6;
  const int lane = tid & 63;

  // ---- XCD-aware swizzle on 1-D grid (nwg % 8 == 0 for every launch) ----
  const int nwg = (int)gridDim.x;
  const int bid = (int)blockIdx.x;
  const int swz = (bid & 7) * (nwg >> 3) + (bid >> 3);
  int bn, bm, bz;
  if constexpr (EPI == EPI_ND) {       // batch = XCD
    bn = swz & 7; bm = (swz >> 3) & 7; bz = swz >> 6;
  } else {
    const int nbn = N >> 8;            // power of two (4 / 16 / 64)
    const int lnb = 31 - __clz(nbn);
    bn = swz & (nbn - 1); bm = swz >> lnb; bz = 0;
  }
  A += (size_t)bz * strideAz;
  B += (size_t)bz * strideBz;

  const int wm = (wave >> 2) * 128;    // wave's M offset in tile
  const int wn = (wave & 3) * 64;      // wave's N offset in tile

  // ---- staging: per K-tile each thread issues 2 A + 2 B loads.
  // lane l -> row (wave*32 + (l>>2)); SOURCE chunk bank-swizzled:
  // (l&3) ^ ((l>>3)&3).  LDS dest = wave-uniform base + lane*16 (linear).
  const int lr = lane >> 2;            // 0..15
  const int lc = (((lane & 3) ^ ((lane >> 3) & 3))) * 8;  // swizzled src col
  const bf16* Ag0 = A + ((size_t)bm * 256 + wave * 32 + lr) * K + lc;
  const bf16* Bg0 = B + ((size_t)bn * 256 + wave * 32 + lr) * K + lc;
  const size_t K16 = (size_t)16 * K;   // 16 rows
  const int ldsAW = wave * 1024;       // wave's segment (elements)
  const int ldsBW = 32768 + wave * 1024;
  const int NT = K >> 5;               // number of K-tiles (even pow2 >= 4)

  auto stageA = [&](int tt) {
    const int bo = (tt & 3) * 8192;
    const bf16* g = Ag0 + (size_t)(tt & (NT - 1)) * 32;
    async_ld16(g,       &lds[bo + ldsAW]);
    async_ld16(g + K16, &lds[bo + ldsAW + 512]);
  };
  auto stageB = [&](int tt) {
    const int bo = (tt & 3) * 8192;
    const bf16* g = Bg0 + (size_t)(tt & (NT - 1)) * 32;
    async_ld16(g,       &lds[bo + ldsBW]);
    async_ld16(g + K16, &lds[bo + ldsBW + 512]);
  };

  f32x4 acc[8][4];
#pragma unroll
  for (int i = 0; i < 8; ++i)
#pragma unroll
    for (int j = 0; j < 4; ++j) acc[i][j] = {0.f, 0.f, 0.f, 0.f};

  // ---- prologue: stage K-tiles 0,1,2; vmcnt(8) retires tile 0 ----
  stageA(0); stageB(0);
  stageA(1); stageB(1);
  stageA(2); stageB(2);
  __builtin_amdgcn_sched_barrier(0);
  asm volatile("s_waitcnt vmcnt(8)" ::: "memory");
  __builtin_amdgcn_s_barrier();
  __builtin_amdgcn_sched_barrier(0);

  const int fm32 = (lane & 15) * 32;   // fragment row * row-stride
  // read slot = (lane>>4) ^ ((lane>>1)&3)   (bank swizzle, lane-constant)
  const int qs = (((lane >> 4) ^ ((lane >> 1) & 3))) * 8;

  bf16x8 bfrP[4], bfrN[4], afA[4], afB[4];

  // initial reads for tile 0 (post-barrier: tile-0 buffer safe)
  {
    const int ab0 = wm * 32 + fm32 + qs;
    const int bb0 = 32768 + wn * 32 + fm32 + qs;
#pragma unroll
    for (int j = 0; j < 4; ++j) bfrP[j] = *(const bf16x8*)&lds[bb0 + j * 512];
#pragma unroll
    for (int i = 0; i < 4; ++i) afA[i] = *(const bf16x8*)&lds[ab0 + i * 512];
  }
  __builtin_amdgcn_sched_barrier(0);

#define TILE_BODY(t, bfrC, bfrX)                                               \
  {                                                                            \
    const int ab  = ((t) & 3) * 8192 + wm * 32 + fm32 + qs;                    \
    const int abn = (((t) + 1) & 3) * 8192 + wm * 32 + fm32 + qs;              \
    const int bbn = 32768 + (((t) + 1) & 3) * 8192 + wn * 32 + fm32 + qs;      \
    /* ---- phase A ---- */                                                    \
    _Pragma("unroll")                                                          \
    for (int i = 0; i < 4; ++i)                                                \
      afB[i] = *(const bf16x8*)&lds[ab + 2048 + i * 512];                      \
    stageA((t) + 3);                                                           \
    __builtin_amdgcn_sched_barrier(0);                                         \
    asm volatile("s_waitcnt vmcnt(6) lgkmcnt(4)" ::: "memory");                \
    __builtin_amdgcn_sched_barrier(0);                                         \
    __builtin_amdgcn_s_setprio(1);                                             \
    _Pragma("unroll")                                                          \
    for (int i = 0; i < 4; ++i)                                                \
      _Pragma("unroll")                                                        \
      for (int j = 0; j < 4; ++j)                                              \
        acc[i][j] = __builtin_amdgcn_mfma_f32_16x16x32_bf16(                   \
            afA[i], bfrC[j], acc[i][j], 0, 0, 0);                              \
    __builtin_amdgcn_s_setprio(0);                                             \
    __builtin_amdgcn_s_barrier();                                              \
    __builtin_amdgcn_sched_barrier(0);                                         \
    /* ---- phase B ---- */                                                    \
    _Pragma("unroll")                                                          \
    for (int j = 0; j < 4; ++j)                                                \
      bfrX[j] = *(const bf16x8*)&lds[bbn + j * 512];                           \
    _Pragma("unroll")                                                          \
    for (int i = 0; i < 4; ++i)                                                \
      afA[i] = *(const bf16x8*)&lds[abn + i * 512];                            \
    stageB((t) + 3);                                                           \
    __builtin_amdgcn_sched_barrier(0);                                         \
    asm volatile("s_waitcnt lgkmcnt(8)" ::: "memory");                         \
    __builtin_amdgcn_sched_barrier(0);                                         \
    __builtin_amdgcn_s_setprio(1);                                             \
    _Pragma("unroll")                                                          \
    for (int i = 0; i < 4; ++i)                                                \
      _Pragma("unroll")                                                        \
      for (int j = 0; j < 4; ++j)                                              \
        acc[4 + i][j] = __builtin_amdgcn_mfma_f32_16x16x32_bf16(               \
            afB[i], bfrC[j], acc[4 + i][j], 0, 0, 0);                          \
    __builtin_amdgcn_s_setprio(0);                                             \
    __builtin_amdgcn_s_barrier();                                              \
    __builtin_amdgcn_sched_barrier(0);                                         \
  }

  for (int tp = 0; tp < NT; tp += 2) {
    TILE_BODY(tp,     bfrP, bfrN);
    TILE_BODY(tp + 1, bfrN, bfrP);
  }
#undef TILE_BODY

  // ---- epilogue: C/D layout col=lane&15, row=(lane>>4)*4+reg ----
  const int cr = (lane >> 4) * 4;
  const int cc = lane & 15;
#pragma unroll
  for (int i = 0; i < 8; ++i) {
#pragma unroll
    for (int j = 0; j < 4; ++j) {
#pragma unroll
      for (int r = 0; r < 4; ++r) {
        const int gm = bm * 256 + wm + i * 16 + cr + r;
        const int gn = bn * 256 + wn + j * 16 + cc;
        float v = acc[i][j][r];
        if constexpr (EPI == EPI_Q) {
          v += bias[gn];
          Cb[(size_t)gm * N + gn] = __float2bfloat16(v);
        } else if constexpr (EPI == EPI_K) {
          // gm = d, gn = global s. ekvT[b][1024+d][t] = exp(k)
          v = __expf(v + bias[gm]);
          const int b = gn >> 11, t = gn & (TT - 1);
          ekv[((size_t)b << 22) + (size_t)(1024 + gm) * TT + t] =
              __float2bfloat16(v);
        } else if constexpr (EPI == EPI_V) {
          // ekvT[b][d][t] = ek * v
          v += bias[gm];
          const int b = gn >> 11, t = gn & (TT - 1);
          const size_t base = ((size_t)b << 22);
          const float ek =
              __bfloat162float(ekv[base + (size_t)(1024 + gm) * TT + t]);
          ekv[base + (size_t)gm * TT + t] = __float2bfloat16(v * ek);
        } else if constexpr (EPI == EPI_ND) {
          Cb[(size_t)bz * strideCz + (size_t)gm * N + gn] =
              __float2bfloat16(v);
        } else if constexpr (EPI == EPI_MLP1) {
          v = fmaxf(v + bias[gn], 0.0f);
          Cb[(size_t)gm * N + gn] = __float2bfloat16(v);
        } else {  // EPI_MLP2: add == Cf aliasing is safe (read-then-write
          // of the same element within the same thread)
          v += bias[gn] + add[(size_t)gm * N + gn];
          Cf[(size_t)gm * N + gn] = v;
        }
      }
    }
  }
}

// ---------------------------------------------------------------------------
// Transpose + cast fp32 [K,N] -> bf16 [N,K] (LDS tiled)
// ---------------------------------------------------------------------------
__global__ __launch_bounds__(256)
void transpose_cast(const float* __restrict__ W, bf16* __restrict__ Wt,
                    int K, int N)
{
  __shared__ float tile[32][33];
  const int n0 = blockIdx.x * 32, k0 = blockIdx.y * 32;
  const int tx = threadIdx.x, ty = threadIdx.y;  // 32 x 8
#pragma unroll
  for (int i = 0; i < 32; i += 8)
    tile[ty + i][tx] = W[(size_t)(k0 + ty + i) * N + n0 + tx];
  __syncthreads();
#pragma unroll
  for (int i = 0; i < 32; i += 8)
    Wt[(size_t)(n0 + ty + i) * K + k0 + tx] =
        __float2bfloat16(tile[tx][ty + i]);
}

// ---------------------------------------------------------------------------
// ew = exp(pos_bias) as bf16 (global max cancels in num/den ratio)
// ---------------------------------------------------------------------------
__global__ __launch_bounds__(256)
void ew_kernel(const float* __restrict__ pb, bf16* __restrict__ ew)
{
  const size_t gid = (size_t)blockIdx.x * 256 + threadIdx.x;
  const float4 v = *(const float4*)(pb + gid * 4);
  union { bf16 h[4]; unsigned long long u; } pk;
  pk.h[0] = __float2bfloat16(__expf(v.x));
  pk.h[1] = __float2bfloat16(__expf(v.y));
  pk.h[2] = __float2bfloat16(__expf(v.z));
  pk.h[3] = __float2bfloat16(__expf(v.w));
  *(unsigned long long*)(ew + gid * 4) = pk.u;
}

// ---------------------------------------------------------------------------
// LayerNorm over D=1024, one block per row, output bf16
// ---------------------------------------------------------------------------
__global__ __launch_bounds__(256)
void ln_kernel(const float* __restrict__ x, const float* __restrict__ g,
               const float* __restrict__ b, bf16* __restrict__ out)
{
  const int row = blockIdx.x;
  const int tid = threadIdx.x;
  const float4 v = ((const float4*)(x + (size_t)row * DD))[tid];
  float s  = v.x + v.y + v.z + v.w;
  float s2 = v.x * v.x + v.y * v.y + v.z * v.z + v.w * v.w;
#pragma unroll
  for (int o = 32; o; o >>= 1) {
    s  += __shfl_down(s, o);
    s2 += __shfl_down(s2, o);
  }
  __shared__ float red[8];
  if ((tid & 63) == 0) { red[tid >> 6] = s; red[4 + (tid >> 6)] = s2; }
  __syncthreads();
  const float ts  = red[0] + red[1] + red[2] + red[3];
  const float ts2 = red[4] + red[5] + red[6] + red[7];
  const float mu = ts * (1.0f / DD);
  const float rs = rsqrtf(ts2 * (1.0f / DD) - mu * mu + 1e-5f);
  const float4 gv = ((const float4*)g)[tid];
  const float4 bv = ((const float4*)b)[tid];
  union { bf16 h[4]; unsigned long long u; } pk;
  pk.h[0] = __float2bfloat16((v.x - mu) * rs * gv.x + bv.x);
  pk.h[1] = __float2bfloat16((v.y - mu) * rs * gv.y + bv.y);
  pk.h[2] = __float2bfloat16((v.z - mu) * rs * gv.z + bv.z);
  pk.h[3] = __float2bfloat16((v.w - mu) * rs * gv.w + bv.w);
  ((unsigned long long*)(out + (size_t)row * DD))[tid] = pk.u;
}

// ---------------------------------------------------------------------------
// Fused: x2 = sigmoid(q) * num/den + x  (x2 aliases d_out), then
// h2 = LN(x2, g2, b2) -> hout bf16.  One block per row.
// ---------------------------------------------------------------------------
__global__ __launch_bounds__(256)
void combine_ln_kernel(const bf16* __restrict__ q, const bf16* __restrict__ nd,
                       const float* __restrict__ x,
                       const float* __restrict__ g, const float* __restrict__ b,
                       float* __restrict__ x2, bf16* __restrict__ hout)
{
  const int row = blockIdx.x;
  const int tid = threadIdx.x;
  const int c = tid * 4;
  const bf16* ndr = nd + (size_t)row * 2048;
  union { unsigned long long u; bf16 h[4]; } un, ud, uq;
  un.u = *(const unsigned long long*)(ndr + c);
  ud.u = *(const unsigned long long*)(ndr + 1024 + c);
  uq.u = *(const unsigned long long*)(q + (size_t)row * DD + c);
  const float4 xv = *(const float4*)(x + (size_t)row * DD + c);
  float4 o;
  o.x = xv.x + (__bfloat162float(un.h[0]) / __bfloat162float(ud.h[0])) /
                   (1.0f + __expf(-__bfloat162float(uq.h[0])));
  o.y = xv.y + (__bfloat162float(un.h[1]) / __bfloat162float(ud.h[1])) /
                   (1.0f + __expf(-__bfloat162float(uq.h[1])));
  o.z = xv.z + (__bfloat162float(un.h[2]) / __bfloat162float(ud.h[2])) /
                   (1.0f + __expf(-__bfloat162float(uq.h[2])));
  o.w = xv.w + (__bfloat162float(un.h[3]) / __bfloat162float(ud.h[3])) /
                   (1.0f + __expf(-__bfloat162float(uq.h[3])));
  *(float4*)(x2 + (size_t)row * DD + c) = o;

  // ---- LayerNorm of o across the row ----
  float s  = o.x + o.y + o.z + o.w;
  float s2 = o.x * o.x + o.y * o.y + o.z * o.z + o.w * o.w;
#pragma unroll
  for (int off = 32; off; off >>= 1) {
    s  += __shfl_down(s, off);
    s2 += __shfl_down(s2, off);
  }
  __shared__ float red[8];
  if ((tid & 63) == 0) { red[tid >> 6] = s; red[4 + (tid >> 6)] = s2; }
  __syncthreads();
  const float ts  = red[0] + red[1] + red[2] + red[3];
  const float ts2 = red[4] + red[5] + red[6] + red[7];
  const float mu = ts * (1.0f / DD);
  const float rs = rsqrtf(ts2 * (1.0f / DD) - mu * mu + 1e-5f);
  const float4 gv = ((const float4*)g)[tid];
  const float4 bv = ((const float4*)b)[tid];
  union { bf16 h[4]; unsigned long long u; } pk;
  pk.h[0] = __float2bfloat16((o.x - mu) * rs * gv.x + bv.x);
  pk.h[1] = __float2bfloat16((o.y - mu) * rs * gv.y + bv.y);
  pk.h[2] = __float2bfloat16((o.z - mu) * rs * gv.z + bv.z);
  pk.h[3] = __float2bfloat16((o.w - mu) * rs * gv.w + bv.w);
  ((unsigned long long*)(hout + (size_t)row * DD))[tid] = pk.u;
}

// ---------------------------------------------------------------------------
extern "C" void kernel_launch(void* const* d_in, const int* in_sizes, int n_in,
                              void* d_out, int out_size, void* d_ws,
                              size_t ws_size, hipStream_t stream)
{
  (void)in_sizes; (void)n_in; (void)out_size; (void)ws_size;
  const float* x   = (const float*)d_in[0];
  const float* Wq  = (const float*)d_in[1];
  const float* bq  = (const float*)d_in[2];
  const float* Wk  = (const float*)d_in[3];
  const float* bk  = (const float*)d_in[4];
  const float* Wv  = (const float*)d_in[5];
  const float* bv  = (const float*)d_in[6];
  const float* pb  = (const float*)d_in[7];
  const float* g1  = (const float*)d_in[8];
  const float* be1 = (const float*)d_in[9];
  const float* W1  = (const float*)d_in[10];
  const float* bm1 = (const float*)d_in[11];
  const float* W2  = (const float*)d_in[12];
  const float* bm2 = (const float*)d_in[13];
  const float* g2  = (const float*)d_in[14];
  const float* be2 = (const float*)d_in[15];
  float* out = (float*)d_out;

  // ---- workspace layout: 222 MiB total ----
  const size_t MiB = 1024 * 1024;
  char* w = (char*)d_ws;
  bf16* hbf = (bf16*)w;  w += (size_t)MM * DD * 2;        // 32 MiB (h, then h2)
  bf16* wqt = (bf16*)w;  w += (size_t)DD * DD * 2;        // 2 MiB
  bf16* wkt = (bf16*)w;  w += (size_t)DD * DD * 2;
  bf16* wvt = (bf16*)w;  w += (size_t)DD * DD * 2;
  bf16* w1t = (bf16*)w;  w += (size_t)4096 * DD * 2;      // 8 MiB
  bf16* w2t = (bf16*)w;  w += (size_t)DD * 4096 * 2;      // 8 MiB
  // scratch region (168 MiB), fully dead after combine_ln_kernel:
  char* scr = w;
  bf16* qbf = (bf16*)scr;                                  // 32 MiB
  bf16* ewb = (bf16*)(scr + 32 * MiB);                     // 8 MiB
  bf16* ekv = (bf16*)(scr + 40 * MiB);   // 64 MiB [b][2048: 0..1023=ek*v, 1024..2047=ek][t]
  bf16* nd  = (bf16*)(scr + 104 * MiB);  // 64 MiB [b][t][2048: num|den]
  bf16* mid = (bf16*)scr;                // 128 MiB, overlays scratch after combine
  float* x2 = out;                       // alias: residual lives in d_out

  const dim3 tb(32, 8);
  transpose_cast<<<dim3(DD / 32, DD / 32), tb, 0, stream>>>(Wq, wqt, DD, DD);
  transpose_cast<<<dim3(DD / 32, DD / 32), tb, 0, stream>>>(Wk, wkt, DD, DD);
  transpose_cast<<<dim3(DD / 32, DD / 32), tb, 0, stream>>>(Wv, wvt, DD, DD);
  transpose_cast<<<dim3(4096 / 32, DD / 32), tb, 0, stream>>>(W1, w1t, DD, 4096);
  transpose_cast<<<dim3(DD / 32, 4096 / 32), tb, 0, stream>>>(W2, w2t, 4096, DD);

  ew_kernel<<<(TT * TT / 4) / 256, 256, 0, stream>>>(pb, ewb);
  ln_kernel<<<MM, 256, 0, stream>>>(x, g1, be1, hbf);

  // q = h @ Wq + bq  -> qbf [16384,1024] bf16
  gemm_bt<EPI_Q><<<(MM / 256) * (DD / 256), 512, 0, stream>>>(
      hbf, wqt, MM, DD, DD, 0, 0, nullptr, qbf, 0, bq, nullptr, nullptr);
  // ek^T: C[d, s] = Wkt @ h^T, epilogue exp -> ekv rows 1024..2047
  gemm_bt<EPI_K><<<(DD / 256) * (MM / 256), 512, 0, stream>>>(
      wkt, hbf, DD, MM, DD, 0, 0, nullptr, nullptr, 0, bk, nullptr, ekv);
  // v^T: epilogue *ek -> ekv rows 0..1023
  gemm_bt<EPI_V><<<(DD / 256) * (MM / 256), 512, 0, stream>>>(
      wvt, hbf, DD, MM, DD, 0, 0, nullptr, nullptr, 0, bv, nullptr, ekv);
  // nd[b] = ew @ ekv[b]^T : [2048,2048] bf16 per batch (XCD = batch)
  gemm_bt<EPI_ND><<<BB * (TT / 256) * (TT / 256), 512, 0, stream>>>(
      ewb, ekv, TT, TT, TT, 0, (long long)TT * TT, nullptr, nd,
      (long long)TT * TT, nullptr, nullptr, nullptr);

  // fused: x2 = sigmoid(q)*num/den + x ; hbf = LN(x2)
  combine_ln_kernel<<<MM, 256, 0, stream>>>(qbf, nd, x, g2, be2, x2, hbf);

  // mid = relu(h2 @ W1 + b1) bf16 [16384,4096]
  gemm_bt<EPI_MLP1><<<(MM / 256) * (4096 / 256), 512, 0, stream>>>(
      hbf, w1t, MM, 4096, DD, 0, 0, nullptr, mid, 0, bm1, nullptr, nullptr);
  // out = mid @ W2 + b2 + x2 fp32 [16384,1024]  (add == Cf, safe)
  gemm_bt<EPI_MLP2><<<(MM / 256) * (DD / 256), 512, 0, stream>>>(
      mid, w2t, MM, DD, 4096, 0, 0, out, nullptr, 0, bm2, x2, nullptr);
}